// Round 16
// baseline (79.521 us; speedup 1.0000x reference)
//
#include <hip/hip_runtime.h>
#include <math.h>

#define NN 8192
#define FF 128
#define CAP 128

typedef float nfloat4 __attribute__((ext_vector_type(4)));
typedef float nfloat2 __attribute__((ext_vector_type(2)));

__device__ __forceinline__ unsigned short f2bf(float f) {
  unsigned u = __float_as_uint(f);
  return (unsigned short)((u + 0x7fffu + ((u >> 16) & 1u)) >> 16);
}

// --- per-row dots f1,f2 + bf16-packed x table ---
__global__ __launch_bounds__(256) void k_scores(const float* __restrict__ x,
                                                const float* __restrict__ a,
                                                float* __restrict__ f1,
                                                float* __restrict__ f2,
                                                unsigned* __restrict__ xb) {
  const int w = threadIdx.x >> 6;
  const int lane = threadIdx.x & 63;
  const int row = blockIdx.x * 4 + w;
  float2 v = ((const float2*)(x + (size_t)row * FF))[lane];
  float2 A1 = ((const float2*)a)[lane];
  float2 A2 = ((const float2*)(a + FF))[lane];
  float s1 = v.x * A1.x + v.y * A1.y;
  float s2 = v.x * A2.x + v.y * A2.y;
  #pragma unroll
  for (int off = 32; off > 0; off >>= 1) {
    s1 += __shfl_down(s1, off);
    s2 += __shfl_down(s2, off);
  }
  if (lane == 0) { f1[row] = s1; f2[row] = s2; }
  xb[(row << 6) + lane] = (unsigned)f2bf(v.x) | ((unsigned)f2bf(v.y) << 16);
}

// --- 2 rows per wave, software-pipelined: stream B chunks hide SpMM-A chains.
__global__ __launch_bounds__(256, 4) void k_scanfwd2(
    const float* __restrict__ adj, const float* __restrict__ x,
    const unsigned* __restrict__ xb,
    const float* __restrict__ f1g, const float* __restrict__ f2g,
    const float* __restrict__ temp,
    int* __restrict__ nnzg, int* __restrict__ colsg, float* __restrict__ valsg,
    float* __restrict__ rowsumg, float* __restrict__ featg,
    unsigned* __restrict__ featb) {
  const int w = threadIdx.x >> 6;
  const int lane = threadIdx.x & 63;
  const int rowA = blockIdx.x * 8 + w * 2;
  const int rowB = rowA + 1;
  const int slA = w * 2, slB = slA + 1;

  __shared__ int   s_c[8][CAP];
  __shared__ float s_u[8][CAP];

  const unsigned long long lt = (1ull << lane) - 1ull;
  const nfloat4* arowA = (const nfloat4*)(adj + (size_t)rowA * NN);
  const nfloat4* arowB = (const nfloat4*)(adj + (size_t)rowB * NN);
  const float coe2 = 1.f / (1.f + expf(-temp[2]));

  // ---------- Phase 1: stream + compact row A ----------
  int runA = 0;
  #pragma unroll 8
  for (int it = 0; it < 32; ++it) {
    nfloat4 v = arowA[it * 64 + lane];
    bool c0 = v.x > 0.f, c1 = v.y > 0.f, c2 = v.z > 0.f, c3 = v.w > 0.f;
    unsigned long long b0 = __ballot(c0), b1 = __ballot(c1),
                       b2 = __ballot(c2), b3 = __ballot(c3);
    int pos = runA + __popcll(b0 & lt) + __popcll(b1 & lt) +
                     __popcll(b2 & lt) + __popcll(b3 & lt);
    int j0 = (it * 64 + lane) * 4;
    if (c0) { if (pos < CAP) s_c[slA][pos] = j0;     pos++; }
    if (c1) { if (pos < CAP) s_c[slA][pos] = j0 + 1; pos++; }
    if (c2) { if (pos < CAP) s_c[slA][pos] = j0 + 2; pos++; }
    if (c3) { if (pos < CAP) s_c[slA][pos] = j0 + 3; pos++; }
    runA += __popcll(b0) + __popcll(b1) + __popcll(b2) + __popcll(b3);
  }
  const int cntA = runA < CAP ? runA : CAP;

  // ---------- Phase 2/3: stream B in chunks; softmax A + SpMM A in gaps ----------
  nfloat4 bb[8];
  int runB = 0;
  float accA0 = 0.f, accA1 = 0.f;
  int ka = 0;

#define LOAD_CHUNK(base) { _Pragma("unroll") \
    for (int i = 0; i < 8; ++i) bb[i] = arowB[((base) + i) * 64 + lane]; }

#define PROC_CHUNK(base) { _Pragma("unroll") \
    for (int i = 0; i < 8; ++i) { \
      nfloat4 v = bb[i]; \
      bool c0 = v.x > 0.f, c1 = v.y > 0.f, c2 = v.z > 0.f, c3 = v.w > 0.f; \
      unsigned long long b0 = __ballot(c0), b1 = __ballot(c1), \
                         b2 = __ballot(c2), b3 = __ballot(c3); \
      int pos = runB + __popcll(b0 & lt) + __popcll(b1 & lt) + \
                       __popcll(b2 & lt) + __popcll(b3 & lt); \
      int j0 = (((base) + i) * 64 + lane) * 4; \
      if (c0) { if (pos < CAP) s_c[slB][pos] = j0;     pos++; } \
      if (c1) { if (pos < CAP) s_c[slB][pos] = j0 + 1; pos++; } \
      if (c2) { if (pos < CAP) s_c[slB][pos] = j0 + 2; pos++; } \
      if (c3) { if (pos < CAP) s_c[slB][pos] = j0 + 3; pos++; } \
      runB += __popcll(b0) + __popcll(b1) + __popcll(b2) + __popcll(b3); } }

#define ROUND_A_BODY { \
      int   c0 = s_c[slA][ka],   c1 = s_c[slA][ka+1], c2 = s_c[slA][ka+2], c3 = s_c[slA][ka+3]; \
      int   c4 = s_c[slA][ka+4], c5 = s_c[slA][ka+5], c6 = s_c[slA][ka+6], c7 = s_c[slA][ka+7]; \
      float w0 = s_u[slA][ka],   w1 = s_u[slA][ka+1], w2 = s_u[slA][ka+2], w3 = s_u[slA][ka+3]; \
      float w4 = s_u[slA][ka+4], w5 = s_u[slA][ka+5], w6 = s_u[slA][ka+6], w7 = s_u[slA][ka+7]; \
      unsigned g0 = xb[(c0 << 6) + lane], g1 = xb[(c1 << 6) + lane]; \
      unsigned g2 = xb[(c2 << 6) + lane], g3 = xb[(c3 << 6) + lane]; \
      unsigned g4 = xb[(c4 << 6) + lane], g5 = xb[(c5 << 6) + lane]; \
      unsigned g6 = xb[(c6 << 6) + lane], g7 = xb[(c7 << 6) + lane]; \
      accA0 += w0 * __uint_as_float(g0 << 16) + w1 * __uint_as_float(g1 << 16) \
             + w2 * __uint_as_float(g2 << 16) + w3 * __uint_as_float(g3 << 16) \
             + w4 * __uint_as_float(g4 << 16) + w5 * __uint_as_float(g5 << 16) \
             + w6 * __uint_as_float(g6 << 16) + w7 * __uint_as_float(g7 << 16); \
      accA1 += w0 * __uint_as_float(g0 & 0xffff0000u) + w1 * __uint_as_float(g1 & 0xffff0000u) \
             + w2 * __uint_as_float(g2 & 0xffff0000u) + w3 * __uint_as_float(g3 & 0xffff0000u) \
             + w4 * __uint_as_float(g4 & 0xffff0000u) + w5 * __uint_as_float(g5 & 0xffff0000u) \
             + w6 * __uint_as_float(g6 & 0xffff0000u) + w7 * __uint_as_float(g7 & 0xffff0000u); \
      ka += 8; }

  LOAD_CHUNK(0);

  // softmax A (f2 gathers + shuffles) while chunk-0 loads are in flight
  float rsA;
  {
    const float F1 = f1g[rowA];
    const int i0 = lane, i1 = lane + 64;
    int col0 = (i0 < cntA) ? s_c[slA][i0] : 0;
    int col1 = (i1 < cntA) ? s_c[slA][i1] : 0;
    float e0 = -INFINITY, e1 = -INFINITY;
    if (i0 < cntA) { float s = F1 + f2g[col0]; e0 = s > 0.f ? s : 0.2f * s; }
    if (i1 < cntA) { float s = F1 + f2g[col1]; e1 = s > 0.f ? s : 0.2f * s; }
    float mx = fmaxf(e0, e1);
    #pragma unroll
    for (int off = 32; off > 0; off >>= 1) mx = fmaxf(mx, __shfl_xor(mx, off));
    float p0 = (i0 < cntA) ? expf(e0 - mx) : 0.f;
    float p1 = (i1 < cntA) ? expf(e1 - mx) : 0.f;
    float sm = p0 + p1;
    #pragma unroll
    for (int off = 32; off > 0; off >>= 1) sm += __shfl_xor(sm, off);
    float inv = 1.f / sm;
    float u0 = p0 * inv, u1 = p1 * inv;
    float q = u0 * u0 + u1 * u1;
    #pragma unroll
    for (int off = 32; off > 0; off >>= 1) q += __shfl_xor(q, off);
    rsA = 0.5f * q;
    if (i0 < cntA) { s_u[slA][i0] = u0; colsg[(size_t)rowA * CAP + i0] = col0;
                     valsg[(size_t)rowA * CAP + i0] = u0; }
    if (i1 < cntA) { s_u[slA][i1] = u1; colsg[(size_t)rowA * CAP + i1] = col1;
                     valsg[(size_t)rowA * CAP + i1] = u1; }
    if (lane == 0) { nnzg[rowA] = cntA; rowsumg[rowA] = rsA; }
  }

  PROC_CHUNK(0);
  LOAD_CHUNK(8);
  if (ka + 7 < cntA) ROUND_A_BODY;
  if (ka + 7 < cntA) ROUND_A_BODY;
  PROC_CHUNK(8);
  LOAD_CHUNK(16);
  if (ka + 7 < cntA) ROUND_A_BODY;
  if (ka + 7 < cntA) ROUND_A_BODY;
  PROC_CHUNK(16);
  LOAD_CHUNK(24);
  if (ka + 7 < cntA) ROUND_A_BODY;
  if (ka + 7 < cntA) ROUND_A_BODY;
  PROC_CHUNK(24);
  const int cntB = runB < CAP ? runB : CAP;

  // finish SpMM A
  while (ka + 7 < cntA) ROUND_A_BODY;
  for (; ka < cntA; ++ka) {
    int c = s_c[slA][ka]; float u = s_u[slA][ka];
    unsigned g = xb[(c << 6) + lane];
    accA0 += u * __uint_as_float(g << 16);
    accA1 += u * __uint_as_float(g & 0xffff0000u);
  }

  // lifting A + writes
  {
    float2 xv = ((const float2*)x)[(rowA << 6) + lane];
    float f0 = accA0 - xv.x * rsA + (1.f - coe2) * xv.x;
    float f1v = accA1 - xv.y * rsA + (1.f - coe2) * xv.y;
    float2 fv; fv.x = f0; fv.y = f1v;
    ((float2*)featg)[(rowA << 6) + lane] = fv;
    featb[(rowA << 6) + lane] = (unsigned)f2bf(f0) | ((unsigned)f2bf(f1v) << 16);
  }

  // ---------- softmax B + persist ----------
  float rsB;
  {
    const float F1 = f1g[rowB];
    const int i0 = lane, i1 = lane + 64;
    int col0 = (i0 < cntB) ? s_c[slB][i0] : 0;
    int col1 = (i1 < cntB) ? s_c[slB][i1] : 0;
    float e0 = -INFINITY, e1 = -INFINITY;
    if (i0 < cntB) { float s = F1 + f2g[col0]; e0 = s > 0.f ? s : 0.2f * s; }
    if (i1 < cntB) { float s = F1 + f2g[col1]; e1 = s > 0.f ? s : 0.2f * s; }
    float mx = fmaxf(e0, e1);
    #pragma unroll
    for (int off = 32; off > 0; off >>= 1) mx = fmaxf(mx, __shfl_xor(mx, off));
    float p0 = (i0 < cntB) ? expf(e0 - mx) : 0.f;
    float p1 = (i1 < cntB) ? expf(e1 - mx) : 0.f;
    float sm = p0 + p1;
    #pragma unroll
    for (int off = 32; off > 0; off >>= 1) sm += __shfl_xor(sm, off);
    float inv = 1.f / sm;
    float u0 = p0 * inv, u1 = p1 * inv;
    float q = u0 * u0 + u1 * u1;
    #pragma unroll
    for (int off = 32; off > 0; off >>= 1) q += __shfl_xor(q, off);
    rsB = 0.5f * q;
    if (i0 < cntB) { s_u[slB][i0] = u0; colsg[(size_t)rowB * CAP + i0] = col0;
                     valsg[(size_t)rowB * CAP + i0] = u0; }
    if (i1 < cntB) { s_u[slB][i1] = u1; colsg[(size_t)rowB * CAP + i1] = col1;
                     valsg[(size_t)rowB * CAP + i1] = u1; }
    if (lane == 0) { nnzg[rowB] = cntB; rowsumg[rowB] = rsB; }
  }

  // ---------- SpMM B + lifting B ----------
  float acc0 = 0.f, acc1 = 0.f;
  int k = 0;
  for (; k + 7 < cntB; k += 8) {
    int   c0 = s_c[slB][k],   c1 = s_c[slB][k+1], c2 = s_c[slB][k+2], c3 = s_c[slB][k+3];
    int   c4 = s_c[slB][k+4], c5 = s_c[slB][k+5], c6 = s_c[slB][k+6], c7 = s_c[slB][k+7];
    float w0 = s_u[slB][k],   w1 = s_u[slB][k+1], w2 = s_u[slB][k+2], w3 = s_u[slB][k+3];
    float w4 = s_u[slB][k+4], w5 = s_u[slB][k+5], w6 = s_u[slB][k+6], w7 = s_u[slB][k+7];
    unsigned g0 = xb[(c0 << 6) + lane], g1 = xb[(c1 << 6) + lane];
    unsigned g2 = xb[(c2 << 6) + lane], g3 = xb[(c3 << 6) + lane];
    unsigned g4 = xb[(c4 << 6) + lane], g5 = xb[(c5 << 6) + lane];
    unsigned g6 = xb[(c6 << 6) + lane], g7 = xb[(c7 << 6) + lane];
    acc0 += w0 * __uint_as_float(g0 << 16) + w1 * __uint_as_float(g1 << 16)
          + w2 * __uint_as_float(g2 << 16) + w3 * __uint_as_float(g3 << 16)
          + w4 * __uint_as_float(g4 << 16) + w5 * __uint_as_float(g5 << 16)
          + w6 * __uint_as_float(g6 << 16) + w7 * __uint_as_float(g7 << 16);
    acc1 += w0 * __uint_as_float(g0 & 0xffff0000u) + w1 * __uint_as_float(g1 & 0xffff0000u)
          + w2 * __uint_as_float(g2 & 0xffff0000u) + w3 * __uint_as_float(g3 & 0xffff0000u)
          + w4 * __uint_as_float(g4 & 0xffff0000u) + w5 * __uint_as_float(g5 & 0xffff0000u)
          + w6 * __uint_as_float(g6 & 0xffff0000u) + w7 * __uint_as_float(g7 & 0xffff0000u);
  }
  for (; k < cntB; ++k) {
    int c = s_c[slB][k]; float u = s_u[slB][k];
    unsigned g = xb[(c << 6) + lane];
    acc0 += u * __uint_as_float(g << 16);
    acc1 += u * __uint_as_float(g & 0xffff0000u);
  }
  {
    float2 xv = ((const float2*)x)[(rowB << 6) + lane];
    float f0 = acc0 - xv.x * rsB + (1.f - coe2) * xv.x;
    float f1v = acc1 - xv.y * rsB + (1.f - coe2) * xv.y;
    float2 fv; fv.x = f0; fv.y = f1v;
    ((float2*)featg)[(rowB << 6) + lane] = fv;
    featb[(rowB << 6) + lane] = (unsigned)f2bf(f0) | ((unsigned)f2bf(f1v) << 16);
  }
#undef LOAD_CHUNK
#undef PROC_CHUNK
#undef ROUND_A_BODY
}

// --- wave-per-row: SpMM U@feat (bf16 table) + inverse lifting + blend (R12) ---
__global__ __launch_bounds__(256, 4) void k_bwd(
    const float* __restrict__ featg, const unsigned* __restrict__ featb,
    const float* __restrict__ h0, const float* __restrict__ temp,
    const int* __restrict__ nnzg, const int* __restrict__ colsg,
    const float* __restrict__ valsg, const float* __restrict__ rowsumg,
    float* __restrict__ out) {
  const int w = threadIdx.x >> 6;
  const int lane = threadIdx.x & 63;
  const int row = blockIdx.x * 4 + w;

  __shared__ int   s_c[4][CAP];
  __shared__ float s_u[4][CAP];

  const int cnt = nnzg[row];
  const int* cg = colsg + (size_t)row * CAP;
  const float* vg = valsg + (size_t)row * CAP;
  const int i0 = lane, i1 = lane + 64;
  if (i0 < cnt) { s_c[w][i0] = cg[i0]; s_u[w][i0] = vg[i0]; }
  if (i1 < cnt) { s_c[w][i1] = cg[i1]; s_u[w][i1] = vg[i1]; }

  const float rs = rowsumg[row];
  float2 ft = ((const float2*)featg)[(row << 6) + lane];
  nfloat2 h = __builtin_nontemporal_load(((const nfloat2*)h0) + (row << 6) + lane);
  const float coe1 = 1.f / (1.f + expf(-temp[1]));
  const float coe3 = 1.f / (1.f + expf(-temp[3]));

  float acc0 = 0.f, acc1 = 0.f;
  int k = 0;
  for (; k + 7 < cnt; k += 8) {
    int   c0 = s_c[w][k],   c1 = s_c[w][k+1], c2 = s_c[w][k+2], c3 = s_c[w][k+3];
    int   c4 = s_c[w][k+4], c5 = s_c[w][k+5], c6 = s_c[w][k+6], c7 = s_c[w][k+7];
    float w0 = s_u[w][k],   w1 = s_u[w][k+1], w2 = s_u[w][k+2], w3 = s_u[w][k+3];
    float w4 = s_u[w][k+4], w5 = s_u[w][k+5], w6 = s_u[w][k+6], w7 = s_u[w][k+7];
    unsigned g0 = featb[(c0 << 6) + lane], g1 = featb[(c1 << 6) + lane];
    unsigned g2 = featb[(c2 << 6) + lane], g3 = featb[(c3 << 6) + lane];
    unsigned g4 = featb[(c4 << 6) + lane], g5 = featb[(c5 << 6) + lane];
    unsigned g6 = featb[(c6 << 6) + lane], g7 = featb[(c7 << 6) + lane];
    acc0 += w0 * __uint_as_float(g0 << 16) + w1 * __uint_as_float(g1 << 16)
          + w2 * __uint_as_float(g2 << 16) + w3 * __uint_as_float(g3 << 16)
          + w4 * __uint_as_float(g4 << 16) + w5 * __uint_as_float(g5 << 16)
          + w6 * __uint_as_float(g6 << 16) + w7 * __uint_as_float(g7 << 16);
    acc1 += w0 * __uint_as_float(g0 & 0xffff0000u) + w1 * __uint_as_float(g1 & 0xffff0000u)
          + w2 * __uint_as_float(g2 & 0xffff0000u) + w3 * __uint_as_float(g3 & 0xffff0000u)
          + w4 * __uint_as_float(g4 & 0xffff0000u) + w5 * __uint_as_float(g5 & 0xffff0000u)
          + w6 * __uint_as_float(g6 & 0xffff0000u) + w7 * __uint_as_float(g7 & 0xffff0000u);
  }
  for (; k < cnt; ++k) {
    int c = s_c[w][k]; float u = s_u[w][k];
    unsigned g = featb[(c << 6) + lane];
    acc0 += u * __uint_as_float(g << 16);
    acc1 += u * __uint_as_float(g & 0xffff0000u);
  }

  float odd0 = ft.x - acc0, odd1 = ft.y - acc1;
  float ev0 = coe3 * acc0 + odd0 * rs;
  float ev1 = coe3 * acc1 + odd1 * rs;
  float fp0 = coe1 * ev0 + (1.f - coe1) * odd0;
  float fp1 = coe1 * ev1 + (1.f - coe1) * odd1;
  nfloat2 o;
  o.x = 0.2f * fp0 + 0.8f * h.x;
  o.y = 0.2f * fp1 + 0.8f * h.y;
  __builtin_nontemporal_store(o, ((nfloat2*)out) + (row << 6) + lane);
}

extern "C" void kernel_launch(void* const* d_in, const int* in_sizes, int n_in,
                              void* d_out, int out_size, void* d_ws, size_t ws_size,
                              hipStream_t stream) {
  const float* x    = (const float*)d_in[0];
  const float* h0   = (const float*)d_in[1];
  const float* adj  = (const float*)d_in[2];
  const float* a    = (const float*)d_in[3];
  const float* temp = (const float*)d_in[4];
  float* out = (float*)d_out;

  float* f1 = (float*)d_ws;                         // 32 KB
  float* f2 = f1 + NN;                              // 32 KB
  float* rowsum = f2 + NN;                          // 32 KB
  int*   nnz = (int*)(rowsum + NN);                 // 32 KB
  int*   cols = nnz + NN;                           // 4 MB
  float* vals = (float*)(cols + (size_t)NN * CAP);  // 4 MB
  float* feat = vals + (size_t)NN * CAP;            // 4 MB
  unsigned* xb = (unsigned*)(feat + (size_t)NN * FF);   // 2 MB
  unsigned* featb = xb + (size_t)NN * 64;               // 2 MB

  k_scores<<<NN / 4, 256, 0, stream>>>(x, a, f1, f2, xb);
  k_scanfwd2<<<NN / 8, 256, 0, stream>>>(adj, x, xb, f1, f2, temp, nnz, cols, vals, rowsum, feat, featb);
  k_bwd<<<NN / 4, 256, 0, stream>>>(feat, featb, h0, temp, nnz, cols, vals, rowsum, out);
}

// Round 17
// 71.141 us; speedup vs baseline: 1.1178x; 1.1178x over previous
//
#include <hip/hip_runtime.h>
#include <math.h>

#define NN 8192
#define FF 128
#define CAP 128

typedef float nfloat4 __attribute__((ext_vector_type(4)));
typedef float nfloat2 __attribute__((ext_vector_type(2)));

__device__ __forceinline__ unsigned short f2bf(float f) {
  unsigned u = __float_as_uint(f);
  return (unsigned short)((u + 0x7fffu + ((u >> 16) & 1u)) >> 16);
}

// --- per-row dots f1,f2 + bf16-packed x table ---
__global__ __launch_bounds__(256) void k_scores(const float* __restrict__ x,
                                                const float* __restrict__ a,
                                                float* __restrict__ f1,
                                                float* __restrict__ f2,
                                                unsigned* __restrict__ xb) {
  const int w = threadIdx.x >> 6;
  const int lane = threadIdx.x & 63;
  const int row = blockIdx.x * 4 + w;
  float2 v = ((const float2*)(x + (size_t)row * FF))[lane];
  float2 A1 = ((const float2*)a)[lane];
  float2 A2 = ((const float2*)(a + FF))[lane];
  float s1 = v.x * A1.x + v.y * A1.y;
  float s2 = v.x * A2.x + v.y * A2.y;
  #pragma unroll
  for (int off = 32; off > 0; off >>= 1) {
    s1 += __shfl_down(s1, off);
    s2 += __shfl_down(s2, off);
  }
  if (lane == 0) { f1[row] = s1; f2[row] = s2; }
  xb[(row << 6) + lane] = (unsigned)f2bf(v.x) | ((unsigned)f2bf(v.y) << 16);
}

// --- wave-per-row: stream adj row, ballot compaction, wave softmax,
//     fused fwd SpMM over bf16 x table + forward lifting.
//     R12 + round-0 gather prefetch under the softmax chain.
__global__ __launch_bounds__(256, 4) void k_scanfwd(
    const float* __restrict__ adj, const float* __restrict__ x,
    const unsigned* __restrict__ xb,
    const float* __restrict__ f1g, const float* __restrict__ f2g,
    const float* __restrict__ temp,
    int* __restrict__ nnzg, int* __restrict__ colsg, float* __restrict__ valsg,
    float* __restrict__ rowsumg, float* __restrict__ featg,
    unsigned* __restrict__ featb) {
  const int w = threadIdx.x >> 6;
  const int lane = threadIdx.x & 63;
  const int row = blockIdx.x * 4 + w;

  __shared__ int   s_c[4][CAP];
  __shared__ float s_u[4][CAP];

  // hoisted independent row-local loads (latency hides under the stream)
  const float F1 = f1g[row];
  float2 xv = ((const float2*)x)[(row << 6) + lane];

  const nfloat4* arow = (const nfloat4*)(adj + (size_t)row * NN);
  const unsigned long long lt = (1ull << lane) - 1ull;
  int run = 0;
  #pragma unroll 8
  for (int it = 0; it < 32; ++it) {
    nfloat4 v = arow[it * 64 + lane];
    bool c0 = v.x > 0.f, c1 = v.y > 0.f, c2 = v.z > 0.f, c3 = v.w > 0.f;
    unsigned long long b0 = __ballot(c0), b1 = __ballot(c1),
                       b2 = __ballot(c2), b3 = __ballot(c3);
    int pos = run + __popcll(b0 & lt) + __popcll(b1 & lt) +
                    __popcll(b2 & lt) + __popcll(b3 & lt);
    int j0 = (it * 64 + lane) * 4;
    if (c0) { if (pos < CAP) s_c[w][pos] = j0;     pos++; }
    if (c1) { if (pos < CAP) s_c[w][pos] = j0 + 1; pos++; }
    if (c2) { if (pos < CAP) s_c[w][pos] = j0 + 2; pos++; }
    if (c3) { if (pos < CAP) s_c[w][pos] = j0 + 3; pos++; }
    run += __popcll(b0) + __popcll(b1) + __popcll(b2) + __popcll(b3);
  }
  const int cnt = run < CAP ? run : CAP;

  // ---- prefetch round-0 xb gathers BEFORE softmax (addresses need only s_c) ----
  unsigned pg[8];
  #pragma unroll
  for (int i = 0; i < 8; ++i) {
    int c = (i < cnt) ? s_c[w][i] : 0;
    pg[i] = xb[(c << 6) + lane];
  }

  // ---- wave softmax + rowsum + persist sparse row ----
  const int i0 = lane, i1 = lane + 64;
  int col0 = (i0 < cnt) ? s_c[w][i0] : 0;
  int col1 = (i1 < cnt) ? s_c[w][i1] : 0;
  float e0 = -INFINITY, e1 = -INFINITY;
  if (i0 < cnt) { float s = F1 + f2g[col0]; e0 = s > 0.f ? s : 0.2f * s; }
  if (i1 < cnt) { float s = F1 + f2g[col1]; e1 = s > 0.f ? s : 0.2f * s; }
  float mx = fmaxf(e0, e1);
  #pragma unroll
  for (int off = 32; off > 0; off >>= 1) mx = fmaxf(mx, __shfl_xor(mx, off));
  float p0 = (i0 < cnt) ? expf(e0 - mx) : 0.f;
  float p1 = (i1 < cnt) ? expf(e1 - mx) : 0.f;
  float sm = p0 + p1;
  #pragma unroll
  for (int off = 32; off > 0; off >>= 1) sm += __shfl_xor(sm, off);
  float inv = 1.f / sm;
  float u0 = p0 * inv, u1 = p1 * inv;
  float q = u0 * u0 + u1 * u1;
  #pragma unroll
  for (int off = 32; off > 0; off >>= 1) q += __shfl_xor(q, off);
  const float rs = 0.5f * q;

  if (i0 < cnt) { s_u[w][i0] = u0; colsg[(size_t)row * CAP + i0] = col0;
                  valsg[(size_t)row * CAP + i0] = u0; }
  if (i1 < cnt) { s_u[w][i1] = u1; colsg[(size_t)row * CAP + i1] = col1;
                  valsg[(size_t)row * CAP + i1] = u1; }
  if (lane == 0) { nnzg[row] = cnt; rowsumg[row] = rs; }

  // ---- fwd SpMM: consume prefetched round 0, then 8-wide rounds ----
  float acc0 = 0.f, acc1 = 0.f;
  #pragma unroll
  for (int i = 0; i < 8; ++i) {
    float u = (i < cnt) ? s_u[w][i] : 0.f;
    acc0 += u * __uint_as_float(pg[i] << 16);
    acc1 += u * __uint_as_float(pg[i] & 0xffff0000u);
  }
  int k = 8;
  for (; k + 7 < cnt; k += 8) {
    int   c0 = s_c[w][k],   c1 = s_c[w][k+1], c2 = s_c[w][k+2], c3 = s_c[w][k+3];
    int   c4 = s_c[w][k+4], c5 = s_c[w][k+5], c6 = s_c[w][k+6], c7 = s_c[w][k+7];
    float w0 = s_u[w][k],   w1 = s_u[w][k+1], w2 = s_u[w][k+2], w3 = s_u[w][k+3];
    float w4 = s_u[w][k+4], w5 = s_u[w][k+5], w6 = s_u[w][k+6], w7 = s_u[w][k+7];
    unsigned g0 = xb[(c0 << 6) + lane], g1 = xb[(c1 << 6) + lane];
    unsigned g2 = xb[(c2 << 6) + lane], g3 = xb[(c3 << 6) + lane];
    unsigned g4 = xb[(c4 << 6) + lane], g5 = xb[(c5 << 6) + lane];
    unsigned g6 = xb[(c6 << 6) + lane], g7 = xb[(c7 << 6) + lane];
    acc0 += w0 * __uint_as_float(g0 << 16) + w1 * __uint_as_float(g1 << 16)
          + w2 * __uint_as_float(g2 << 16) + w3 * __uint_as_float(g3 << 16)
          + w4 * __uint_as_float(g4 << 16) + w5 * __uint_as_float(g5 << 16)
          + w6 * __uint_as_float(g6 << 16) + w7 * __uint_as_float(g7 << 16);
    acc1 += w0 * __uint_as_float(g0 & 0xffff0000u) + w1 * __uint_as_float(g1 & 0xffff0000u)
          + w2 * __uint_as_float(g2 & 0xffff0000u) + w3 * __uint_as_float(g3 & 0xffff0000u)
          + w4 * __uint_as_float(g4 & 0xffff0000u) + w5 * __uint_as_float(g5 & 0xffff0000u)
          + w6 * __uint_as_float(g6 & 0xffff0000u) + w7 * __uint_as_float(g7 & 0xffff0000u);
  }
  for (; k < cnt; ++k) {
    int c = s_c[w][k]; float u = s_u[w][k];
    unsigned g = xb[(c << 6) + lane];
    acc0 += u * __uint_as_float(g << 16);
    acc1 += u * __uint_as_float(g & 0xffff0000u);
  }

  const float coe2 = 1.f / (1.f + expf(-temp[2]));
  float ft0 = acc0 - xv.x * rs + (1.f - coe2) * xv.x;
  float ft1 = acc1 - xv.y * rs + (1.f - coe2) * xv.y;
  float2 ftv; ftv.x = ft0; ftv.y = ft1;
  ((float2*)featg)[(row << 6) + lane] = ftv;
  featb[(row << 6) + lane] = (unsigned)f2bf(ft0) | ((unsigned)f2bf(ft1) << 16);
}

// --- wave-per-row: SpMM U@feat (bf16 table) + inverse lifting + blend ---
__global__ __launch_bounds__(256, 4) void k_bwd(
    const float* __restrict__ featg, const unsigned* __restrict__ featb,
    const float* __restrict__ h0, const float* __restrict__ temp,
    const int* __restrict__ nnzg, const int* __restrict__ colsg,
    const float* __restrict__ valsg, const float* __restrict__ rowsumg,
    float* __restrict__ out) {
  const int w = threadIdx.x >> 6;
  const int lane = threadIdx.x & 63;
  const int row = blockIdx.x * 4 + w;

  __shared__ int   s_c[4][CAP];
  __shared__ float s_u[4][CAP];

  const int cnt = nnzg[row];
  const int* cg = colsg + (size_t)row * CAP;
  const float* vg = valsg + (size_t)row * CAP;
  const int i0 = lane, i1 = lane + 64;
  if (i0 < cnt) { s_c[w][i0] = cg[i0]; s_u[w][i0] = vg[i0]; }
  if (i1 < cnt) { s_c[w][i1] = cg[i1]; s_u[w][i1] = vg[i1]; }

  const float rs = rowsumg[row];
  float2 ft = ((const float2*)featg)[(row << 6) + lane];
  nfloat2 h = __builtin_nontemporal_load(((const nfloat2*)h0) + (row << 6) + lane);
  const float coe1 = 1.f / (1.f + expf(-temp[1]));
  const float coe3 = 1.f / (1.f + expf(-temp[3]));

  float acc0 = 0.f, acc1 = 0.f;
  int k = 0;
  for (; k + 7 < cnt; k += 8) {
    int   c0 = s_c[w][k],   c1 = s_c[w][k+1], c2 = s_c[w][k+2], c3 = s_c[w][k+3];
    int   c4 = s_c[w][k+4], c5 = s_c[w][k+5], c6 = s_c[w][k+6], c7 = s_c[w][k+7];
    float w0 = s_u[w][k],   w1 = s_u[w][k+1], w2 = s_u[w][k+2], w3 = s_u[w][k+3];
    float w4 = s_u[w][k+4], w5 = s_u[w][k+5], w6 = s_u[w][k+6], w7 = s_u[w][k+7];
    unsigned g0 = featb[(c0 << 6) + lane], g1 = featb[(c1 << 6) + lane];
    unsigned g2 = featb[(c2 << 6) + lane], g3 = featb[(c3 << 6) + lane];
    unsigned g4 = featb[(c4 << 6) + lane], g5 = featb[(c5 << 6) + lane];
    unsigned g6 = featb[(c6 << 6) + lane], g7 = featb[(c7 << 6) + lane];
    acc0 += w0 * __uint_as_float(g0 << 16) + w1 * __uint_as_float(g1 << 16)
          + w2 * __uint_as_float(g2 << 16) + w3 * __uint_as_float(g3 << 16)
          + w4 * __uint_as_float(g4 << 16) + w5 * __uint_as_float(g5 << 16)
          + w6 * __uint_as_float(g6 << 16) + w7 * __uint_as_float(g7 << 16);
    acc1 += w0 * __uint_as_float(g0 & 0xffff0000u) + w1 * __uint_as_float(g1 & 0xffff0000u)
          + w2 * __uint_as_float(g2 & 0xffff0000u) + w3 * __uint_as_float(g3 & 0xffff0000u)
          + w4 * __uint_as_float(g4 & 0xffff0000u) + w5 * __uint_as_float(g5 & 0xffff0000u)
          + w6 * __uint_as_float(g6 & 0xffff0000u) + w7 * __uint_as_float(g7 & 0xffff0000u);
  }
  for (; k < cnt; ++k) {
    int c = s_c[w][k]; float u = s_u[w][k];
    unsigned g = featb[(c << 6) + lane];
    acc0 += u * __uint_as_float(g << 16);
    acc1 += u * __uint_as_float(g & 0xffff0000u);
  }

  float odd0 = ft.x - acc0, odd1 = ft.y - acc1;
  float ev0 = coe3 * acc0 + odd0 * rs;
  float ev1 = coe3 * acc1 + odd1 * rs;
  float fp0 = coe1 * ev0 + (1.f - coe1) * odd0;
  float fp1 = coe1 * ev1 + (1.f - coe1) * odd1;
  nfloat2 o;
  o.x = 0.2f * fp0 + 0.8f * h.x;
  o.y = 0.2f * fp1 + 0.8f * h.y;
  __builtin_nontemporal_store(o, ((nfloat2*)out) + (row << 6) + lane);
}

extern "C" void kernel_launch(void* const* d_in, const int* in_sizes, int n_in,
                              void* d_out, int out_size, void* d_ws, size_t ws_size,
                              hipStream_t stream) {
  const float* x    = (const float*)d_in[0];
  const float* h0   = (const float*)d_in[1];
  const float* adj  = (const float*)d_in[2];
  const float* a    = (const float*)d_in[3];
  const float* temp = (const float*)d_in[4];
  float* out = (float*)d_out;

  float* f1 = (float*)d_ws;                         // 32 KB
  float* f2 = f1 + NN;                              // 32 KB
  float* rowsum = f2 + NN;                          // 32 KB
  int*   nnz = (int*)(rowsum + NN);                 // 32 KB
  int*   cols = nnz + NN;                           // 4 MB
  float* vals = (float*)(cols + (size_t)NN * CAP);  // 4 MB
  float* feat = vals + (size_t)NN * CAP;            // 4 MB
  unsigned* xb = (unsigned*)(feat + (size_t)NN * FF);   // 2 MB
  unsigned* featb = xb + (size_t)NN * 64;               // 2 MB

  k_scores<<<NN / 4, 256, 0, stream>>>(x, a, f1, f2, xb);
  k_scanfwd<<<NN / 4, 256, 0, stream>>>(adj, x, xb, f1, f2, temp, nnz, cols, vals, rowsum, feat, featb);
  k_bwd<<<NN / 4, 256, 0, stream>>>(feat, featb, h0, temp, nnz, cols, vals, rowsum, out);
}

// Round 18
// 70.743 us; speedup vs baseline: 1.1241x; 1.0056x over previous
//
#include <hip/hip_runtime.h>
#include <math.h>

#define NN 8192
#define FF 128
#define CAP 128

typedef float nfloat4 __attribute__((ext_vector_type(4)));
typedef float nfloat2 __attribute__((ext_vector_type(2)));

__device__ __forceinline__ unsigned short f2bf(float f) {
  unsigned u = __float_as_uint(f);
  return (unsigned short)((u + 0x7fffu + ((u >> 16) & 1u)) >> 16);
}

// --- per-row dots f1,f2 + bf16-packed x table ---
__global__ __launch_bounds__(256) void k_scores(const float* __restrict__ x,
                                                const float* __restrict__ a,
                                                float* __restrict__ f1,
                                                float* __restrict__ f2,
                                                unsigned* __restrict__ xb) {
  const int w = threadIdx.x >> 6;
  const int lane = threadIdx.x & 63;
  const int row = blockIdx.x * 4 + w;
  float2 v = ((const float2*)(x + (size_t)row * FF))[lane];
  float2 A1 = ((const float2*)a)[lane];
  float2 A2 = ((const float2*)(a + FF))[lane];
  float s1 = v.x * A1.x + v.y * A1.y;
  float s2 = v.x * A2.x + v.y * A2.y;
  #pragma unroll
  for (int off = 32; off > 0; off >>= 1) {
    s1 += __shfl_down(s1, off);
    s2 += __shfl_down(s2, off);
  }
  if (lane == 0) { f1[row] = s1; f2[row] = s2; }
  xb[(row << 6) + lane] = (unsigned)f2bf(v.x) | ((unsigned)f2bf(v.y) << 16);
}

// --- wave-per-row: stream adj row, ballot compaction, wave softmax,
//     fused fwd SpMM over bf16 x table + forward lifting.
//     R17 + rounds 0-1 gather prefetch under the softmax chain.
__global__ __launch_bounds__(256, 4) void k_scanfwd(
    const float* __restrict__ adj, const float* __restrict__ x,
    const unsigned* __restrict__ xb,
    const float* __restrict__ f1g, const float* __restrict__ f2g,
    const float* __restrict__ temp,
    int* __restrict__ nnzg, int* __restrict__ colsg, float* __restrict__ valsg,
    float* __restrict__ rowsumg, float* __restrict__ featg,
    unsigned* __restrict__ featb) {
  const int w = threadIdx.x >> 6;
  const int lane = threadIdx.x & 63;
  const int row = blockIdx.x * 4 + w;

  __shared__ int   s_c[4][CAP];
  __shared__ float s_u[4][CAP];

  // hoisted independent row-local loads (latency hides under the stream)
  const float F1 = f1g[row];
  float2 xv = ((const float2*)x)[(row << 6) + lane];

  const nfloat4* arow = (const nfloat4*)(adj + (size_t)row * NN);
  const unsigned long long lt = (1ull << lane) - 1ull;
  int run = 0;
  #pragma unroll 8
  for (int it = 0; it < 32; ++it) {
    nfloat4 v = arow[it * 64 + lane];
    bool c0 = v.x > 0.f, c1 = v.y > 0.f, c2 = v.z > 0.f, c3 = v.w > 0.f;
    unsigned long long b0 = __ballot(c0), b1 = __ballot(c1),
                       b2 = __ballot(c2), b3 = __ballot(c3);
    int pos = run + __popcll(b0 & lt) + __popcll(b1 & lt) +
                    __popcll(b2 & lt) + __popcll(b3 & lt);
    int j0 = (it * 64 + lane) * 4;
    if (c0) { if (pos < CAP) s_c[w][pos] = j0;     pos++; }
    if (c1) { if (pos < CAP) s_c[w][pos] = j0 + 1; pos++; }
    if (c2) { if (pos < CAP) s_c[w][pos] = j0 + 2; pos++; }
    if (c3) { if (pos < CAP) s_c[w][pos] = j0 + 3; pos++; }
    run += __popcll(b0) + __popcll(b1) + __popcll(b2) + __popcll(b3);
  }
  const int cnt = run < CAP ? run : CAP;

  // ---- prefetch rounds 0-1 xb gathers BEFORE softmax (addresses need only s_c) ----
  unsigned pg[16];
  #pragma unroll
  for (int i = 0; i < 16; ++i) {
    int c = (i < cnt) ? s_c[w][i] : 0;
    pg[i] = xb[(c << 6) + lane];
  }

  // ---- wave softmax + rowsum + persist sparse row ----
  const int i0 = lane, i1 = lane + 64;
  int col0 = (i0 < cnt) ? s_c[w][i0] : 0;
  int col1 = (i1 < cnt) ? s_c[w][i1] : 0;
  float e0 = -INFINITY, e1 = -INFINITY;
  if (i0 < cnt) { float s = F1 + f2g[col0]; e0 = s > 0.f ? s : 0.2f * s; }
  if (i1 < cnt) { float s = F1 + f2g[col1]; e1 = s > 0.f ? s : 0.2f * s; }
  float mx = fmaxf(e0, e1);
  #pragma unroll
  for (int off = 32; off > 0; off >>= 1) mx = fmaxf(mx, __shfl_xor(mx, off));
  float p0 = (i0 < cnt) ? expf(e0 - mx) : 0.f;
  float p1 = (i1 < cnt) ? expf(e1 - mx) : 0.f;
  float sm = p0 + p1;
  #pragma unroll
  for (int off = 32; off > 0; off >>= 1) sm += __shfl_xor(sm, off);
  float inv = 1.f / sm;
  float u0 = p0 * inv, u1 = p1 * inv;
  float q = u0 * u0 + u1 * u1;
  #pragma unroll
  for (int off = 32; off > 0; off >>= 1) q += __shfl_xor(q, off);
  const float rs = 0.5f * q;

  if (i0 < cnt) { s_u[w][i0] = u0; colsg[(size_t)row * CAP + i0] = col0;
                  valsg[(size_t)row * CAP + i0] = u0; }
  if (i1 < cnt) { s_u[w][i1] = u1; colsg[(size_t)row * CAP + i1] = col1;
                  valsg[(size_t)row * CAP + i1] = u1; }
  if (lane == 0) { nnzg[row] = cnt; rowsumg[row] = rs; }

  // ---- fwd SpMM: consume prefetched rounds 0-1, then 8-wide rounds ----
  float acc0 = 0.f, acc1 = 0.f;
  #pragma unroll
  for (int i = 0; i < 16; ++i) {
    float u = (i < cnt) ? s_u[w][i] : 0.f;
    acc0 += u * __uint_as_float(pg[i] << 16);
    acc1 += u * __uint_as_float(pg[i] & 0xffff0000u);
  }
  int k = 16;
  for (; k + 7 < cnt; k += 8) {
    int   c0 = s_c[w][k],   c1 = s_c[w][k+1], c2 = s_c[w][k+2], c3 = s_c[w][k+3];
    int   c4 = s_c[w][k+4], c5 = s_c[w][k+5], c6 = s_c[w][k+6], c7 = s_c[w][k+7];
    float w0 = s_u[w][k],   w1 = s_u[w][k+1], w2 = s_u[w][k+2], w3 = s_u[w][k+3];
    float w4 = s_u[w][k+4], w5 = s_u[w][k+5], w6 = s_u[w][k+6], w7 = s_u[w][k+7];
    unsigned g0 = xb[(c0 << 6) + lane], g1 = xb[(c1 << 6) + lane];
    unsigned g2 = xb[(c2 << 6) + lane], g3 = xb[(c3 << 6) + lane];
    unsigned g4 = xb[(c4 << 6) + lane], g5 = xb[(c5 << 6) + lane];
    unsigned g6 = xb[(c6 << 6) + lane], g7 = xb[(c7 << 6) + lane];
    acc0 += w0 * __uint_as_float(g0 << 16) + w1 * __uint_as_float(g1 << 16)
          + w2 * __uint_as_float(g2 << 16) + w3 * __uint_as_float(g3 << 16)
          + w4 * __uint_as_float(g4 << 16) + w5 * __uint_as_float(g5 << 16)
          + w6 * __uint_as_float(g6 << 16) + w7 * __uint_as_float(g7 << 16);
    acc1 += w0 * __uint_as_float(g0 & 0xffff0000u) + w1 * __uint_as_float(g1 & 0xffff0000u)
          + w2 * __uint_as_float(g2 & 0xffff0000u) + w3 * __uint_as_float(g3 & 0xffff0000u)
          + w4 * __uint_as_float(g4 & 0xffff0000u) + w5 * __uint_as_float(g5 & 0xffff0000u)
          + w6 * __uint_as_float(g6 & 0xffff0000u) + w7 * __uint_as_float(g7 & 0xffff0000u);
  }
  for (; k < cnt; ++k) {
    int c = s_c[w][k]; float u = s_u[w][k];
    unsigned g = xb[(c << 6) + lane];
    acc0 += u * __uint_as_float(g << 16);
    acc1 += u * __uint_as_float(g & 0xffff0000u);
  }

  const float coe2 = 1.f / (1.f + expf(-temp[2]));
  float ft0 = acc0 - xv.x * rs + (1.f - coe2) * xv.x;
  float ft1 = acc1 - xv.y * rs + (1.f - coe2) * xv.y;
  float2 ftv; ftv.x = ft0; ftv.y = ft1;
  ((float2*)featg)[(row << 6) + lane] = ftv;
  featb[(row << 6) + lane] = (unsigned)f2bf(ft0) | ((unsigned)f2bf(ft1) << 16);
}

// --- wave-per-row: SpMM U@feat (bf16 table) + inverse lifting + blend ---
__global__ __launch_bounds__(256, 4) void k_bwd(
    const float* __restrict__ featg, const unsigned* __restrict__ featb,
    const float* __restrict__ h0, const float* __restrict__ temp,
    const int* __restrict__ nnzg, const int* __restrict__ colsg,
    const float* __restrict__ valsg, const float* __restrict__ rowsumg,
    float* __restrict__ out) {
  const int w = threadIdx.x >> 6;
  const int lane = threadIdx.x & 63;
  const int row = blockIdx.x * 4 + w;

  __shared__ int   s_c[4][CAP];
  __shared__ float s_u[4][CAP];

  const int cnt = nnzg[row];
  const int* cg = colsg + (size_t)row * CAP;
  const float* vg = valsg + (size_t)row * CAP;
  const int i0 = lane, i1 = lane + 64;
  if (i0 < cnt) { s_c[w][i0] = cg[i0]; s_u[w][i0] = vg[i0]; }
  if (i1 < cnt) { s_c[w][i1] = cg[i1]; s_u[w][i1] = vg[i1]; }

  const float rs = rowsumg[row];
  float2 ft = ((const float2*)featg)[(row << 6) + lane];
  nfloat2 h = __builtin_nontemporal_load(((const nfloat2*)h0) + (row << 6) + lane);
  const float coe1 = 1.f / (1.f + expf(-temp[1]));
  const float coe3 = 1.f / (1.f + expf(-temp[3]));

  float acc0 = 0.f, acc1 = 0.f;
  int k = 0;
  for (; k + 7 < cnt; k += 8) {
    int   c0 = s_c[w][k],   c1 = s_c[w][k+1], c2 = s_c[w][k+2], c3 = s_c[w][k+3];
    int   c4 = s_c[w][k+4], c5 = s_c[w][k+5], c6 = s_c[w][k+6], c7 = s_c[w][k+7];
    float w0 = s_u[w][k],   w1 = s_u[w][k+1], w2 = s_u[w][k+2], w3 = s_u[w][k+3];
    float w4 = s_u[w][k+4], w5 = s_u[w][k+5], w6 = s_u[w][k+6], w7 = s_u[w][k+7];
    unsigned g0 = featb[(c0 << 6) + lane], g1 = featb[(c1 << 6) + lane];
    unsigned g2 = featb[(c2 << 6) + lane], g3 = featb[(c3 << 6) + lane];
    unsigned g4 = featb[(c4 << 6) + lane], g5 = featb[(c5 << 6) + lane];
    unsigned g6 = featb[(c6 << 6) + lane], g7 = featb[(c7 << 6) + lane];
    acc0 += w0 * __uint_as_float(g0 << 16) + w1 * __uint_as_float(g1 << 16)
          + w2 * __uint_as_float(g2 << 16) + w3 * __uint_as_float(g3 << 16)
          + w4 * __uint_as_float(g4 << 16) + w5 * __uint_as_float(g5 << 16)
          + w6 * __uint_as_float(g6 << 16) + w7 * __uint_as_float(g7 << 16);
    acc1 += w0 * __uint_as_float(g0 & 0xffff0000u) + w1 * __uint_as_float(g1 & 0xffff0000u)
          + w2 * __uint_as_float(g2 & 0xffff0000u) + w3 * __uint_as_float(g3 & 0xffff0000u)
          + w4 * __uint_as_float(g4 & 0xffff0000u) + w5 * __uint_as_float(g5 & 0xffff0000u)
          + w6 * __uint_as_float(g6 & 0xffff0000u) + w7 * __uint_as_float(g7 & 0xffff0000u);
  }
  for (; k < cnt; ++k) {
    int c = s_c[w][k]; float u = s_u[w][k];
    unsigned g = featb[(c << 6) + lane];
    acc0 += u * __uint_as_float(g << 16);
    acc1 += u * __uint_as_float(g & 0xffff0000u);
  }

  float odd0 = ft.x - acc0, odd1 = ft.y - acc1;
  float ev0 = coe3 * acc0 + odd0 * rs;
  float ev1 = coe3 * acc1 + odd1 * rs;
  float fp0 = coe1 * ev0 + (1.f - coe1) * odd0;
  float fp1 = coe1 * ev1 + (1.f - coe1) * odd1;
  nfloat2 o;
  o.x = 0.2f * fp0 + 0.8f * h.x;
  o.y = 0.2f * fp1 + 0.8f * h.y;
  __builtin_nontemporal_store(o, ((nfloat2*)out) + (row << 6) + lane);
}

extern "C" void kernel_launch(void* const* d_in, const int* in_sizes, int n_in,
                              void* d_out, int out_size, void* d_ws, size_t ws_size,
                              hipStream_t stream) {
  const float* x    = (const float*)d_in[0];
  const float* h0   = (const float*)d_in[1];
  const float* adj  = (const float*)d_in[2];
  const float* a    = (const float*)d_in[3];
  const float* temp = (const float*)d_in[4];
  float* out = (float*)d_out;

  float* f1 = (float*)d_ws;                         // 32 KB
  float* f2 = f1 + NN;                              // 32 KB
  float* rowsum = f2 + NN;                          // 32 KB
  int*   nnz = (int*)(rowsum + NN);                 // 32 KB
  int*   cols = nnz + NN;                           // 4 MB
  float* vals = (float*)(cols + (size_t)NN * CAP);  // 4 MB
  float* feat = vals + (size_t)NN * CAP;            // 4 MB
  unsigned* xb = (unsigned*)(feat + (size_t)NN * FF);   // 2 MB
  unsigned* featb = xb + (size_t)NN * 64;               // 2 MB

  k_scores<<<NN / 4, 256, 0, stream>>>(x, a, f1, f2, xb);
  k_scanfwd<<<NN / 4, 256, 0, stream>>>(adj, x, xb, f1, f2, temp, nnz, cols, vals, rowsum, feat, featb);
  k_bwd<<<NN / 4, 256, 0, stream>>>(feat, featb, h0, temp, nnz, cols, vals, rowsum, out);
}